// Round 8
// baseline (38.413 us; speedup 1.0000x reference)
//
#include <hip/hip_runtime.h>
#include <math.h>

#define PI_F 3.14159265358979323846f

typedef float f32x4 __attribute__((ext_vector_type(4)));
typedef int   i32x2 __attribute__((ext_vector_type(2)));

// ---------------------------------------------------------------------------
// Cross-lane primitives — all VALU (DPP / permlane / readlane) except the
// init bpermutes. dpp ctrl: quad_perm[1,0,3,2]=0xB1 (xor1), [2,3,0,1]=0x4E
// (xor2), [3,2,1,0]=0x1B (xor3), row_half_mirror=0x141 (xor7),
// row_ror:8=0x128 (xor8).
// ---------------------------------------------------------------------------
template<int CTRL>
static __device__ __forceinline__ float dppf(float v) {
  return __builtin_bit_cast(float,
    __builtin_amdgcn_update_dpp(0, __builtin_bit_cast(int, v), CTRL, 0xF, 0xF, false));
}
static __device__ __forceinline__ float pswap32(float v, int lane) {
  // verified R5: with both operands = v, xor32 = (lane>=32) ? r.x : r.y
  i32x2 r = __builtin_amdgcn_permlane32_swap(
      __builtin_bit_cast(int, v), __builtin_bit_cast(int, v), false, false);
  return __builtin_bit_cast(float, (lane & 32) ? r.x : r.y);
}
static __device__ __forceinline__ float pswap16(float v, int lane) {
  // v_permlane16_swap_b32: swaps odd 16-rows of vdst with even rows of vsrc.
  // With both = v: r.x = odd-row? v[l-16] : v[l]; r.y = even-row? v[l+16] : v[l].
  // xor16 = (lane&16) ? r.x : r.y   (same select pattern as pswap32)
  i32x2 r = __builtin_amdgcn_permlane16_swap(
      __builtin_bit_cast(int, v), __builtin_bit_cast(int, v), false, false);
  return __builtin_bit_cast(float, (lane & 16) ? r.x : r.y);
}

template<int MASK>
static __device__ __forceinline__ float lxor(float v, int lane) {
  if constexpr (MASK == 1)       return dppf<0xB1>(v);
  else if constexpr (MASK == 2)  return dppf<0x4E>(v);
  else if constexpr (MASK == 3)  return dppf<0x1B>(v);
  else if constexpr (MASK == 4)  return dppf<0x1B>(dppf<0x141>(v));            // 7^3
  else if constexpr (MASK == 6)  return dppf<0xB1>(dppf<0x141>(v));            // 7^1
  else if constexpr (MASK == 8)  return dppf<0x128>(v);
  else if constexpr (MASK == 12) return dppf<0x128>(dppf<0x1B>(dppf<0x141>(v))); // 8^4
  else if constexpr (MASK == 16) return pswap16(v, lane);
  else if constexpr (MASK == 24) return pswap16(dppf<0x128>(v), lane);
  else if constexpr (MASK == 32) return pswap32(v, lane);
  else if constexpr (MASK == 48) return pswap16(pswap32(v, lane), lane);
  else return __shfl_xor(v, MASK, 64);
}
// uniform broadcast from lane SRC (valid after full 64-lane reduce) -> SGPR
template<int SRC>
static __device__ __forceinline__ float breadl(float v) {
  return __builtin_bit_cast(float,
    __builtin_amdgcn_readlane(__builtin_bit_cast(int, v), SRC));
}
static __device__ __forceinline__ float xorsgn(float v, int sgn) {
  return __builtin_bit_cast(float, __builtin_bit_cast(int, v) ^ sgn);
}

// ---------------------------------------------------------------------------
// Index algebra identical to R2..R7 (verified): amplitude p = lane*4 + r,
// wires 0..5 = lane bits 5..0, wires 6,7 = r bits 1,0. CNOTs absorbed into
// gate masks via GF(2) relabeling (A1/A2).
// Rot structure: u11 = conj(u00), u10 = -conj(u01) =>
//   coefficients (Ar, ±S, ±T, Bi), S=u00i^plsgn, T=u01r^plsgn;
//   r-parity sign folded into compile-time fma sign.
// ---------------------------------------------------------------------------
template<int R, int LMASK, int RMASK, int HIR>
static __device__ __forceinline__ void gate_step(
    const float ar[4], const float ai[4], float& nr, float& ni,
    float Ar, float S, float T, float Bi, int lane)
{
  constexpr int  rx = R & HIR;
  constexpr bool RP = (rx == 1 || rx == 2);   // parity of 2-bit value
  const float sr = ar[R], si = ai[R];
  float pr, pi;
  if constexpr (LMASK != 0) {
    pr = lxor<LMASK>(ar[R ^ RMASK], lane);
    pi = lxor<LMASK>(ai[R ^ RMASK], lane);
  } else {
    pr = ar[R ^ RMASK]; pi = ai[R ^ RMASK];
  }
  float t = Ar * sr;
  if constexpr (!RP) t = fmaf(-S, si, t); else t = fmaf(S, si, t);
  if constexpr (!RP) t = fmaf( T, pr, t); else t = fmaf(-T, pr, t);
  t = fmaf(-Bi, pi, t);
  nr = t;
  t = Ar * si;
  if constexpr (!RP) t = fmaf(S, sr, t); else t = fmaf(-S, sr, t);
  if constexpr (!RP) t = fmaf(T, pi, t); else t = fmaf(-T, pi, t);
  t = fmaf(Bi, pr, t);
  ni = t;
}

// One gate applied to TWO independent element states (ILP-2).
template<int LMASK, int RMASK, int HIL, int HIR>
static __device__ __forceinline__ void applyGP(
    float arA[4], float aiA[4], float arB[4], float aiB[4],
    const f32x4* __restrict__ g4, int lane)
{
  const f32x4 g = *g4;        // u00r, u00i, u01r, u01i  (SGPR via s_load)
  const float Ar = g.x, Bi = g.w;
  float S = g.y, T = g.z;
  if constexpr (HIL != 0) {   // per-lane sign, shared by both elements
    const int sgn = (__popc(lane & HIL) & 1) << 31;
    S = xorsgn(S, sgn);
    T = xorsgn(T, sgn);
  }
  float nrA[4], niA[4], nrB[4], niB[4];
  gate_step<0, LMASK, RMASK, HIR>(arA, aiA, nrA[0], niA[0], Ar, S, T, Bi, lane);
  gate_step<0, LMASK, RMASK, HIR>(arB, aiB, nrB[0], niB[0], Ar, S, T, Bi, lane);
  gate_step<1, LMASK, RMASK, HIR>(arA, aiA, nrA[1], niA[1], Ar, S, T, Bi, lane);
  gate_step<1, LMASK, RMASK, HIR>(arB, aiB, nrB[1], niB[1], Ar, S, T, Bi, lane);
  gate_step<2, LMASK, RMASK, HIR>(arA, aiA, nrA[2], niA[2], Ar, S, T, Bi, lane);
  gate_step<2, LMASK, RMASK, HIR>(arB, aiB, nrB[2], niB[2], Ar, S, T, Bi, lane);
  gate_step<3, LMASK, RMASK, HIR>(arA, aiA, nrA[3], niA[3], Ar, S, T, Bi, lane);
  gate_step<3, LMASK, RMASK, HIR>(arB, aiB, nrB[3], niB[3], Ar, S, T, Bi, lane);
#pragma unroll
  for (int r = 0; r < 4; ++r) {
    arA[r] = nrA[r]; aiA[r] = niA[r];
    arB[r] = nrB[r]; aiB[r] = niB[r];
  }
}

// ---------------------------------------------------------------------------
// Setup: 16 Rot gates -> 4 floats each: u00r, u00i, u01r, u01i
// ---------------------------------------------------------------------------
__global__ void qbranch_setup(const float* __restrict__ weights,
                              float* __restrict__ gates)
{
  int t = threadIdx.x;
  if (t >= 16) return;
  float phi = weights[t*3 + 0];
  float th  = weights[t*3 + 1];
  float om  = weights[t*3 + 2];
  float ct = cosf(th * 0.5f), st = sinf(th * 0.5f);
  float ap = (phi + om) * 0.5f, am = (phi - om) * 0.5f;
  float* g = gates + t*4;
  g[0] =  cosf(ap)*ct;   // u00r
  g[1] = -sinf(ap)*ct;   // u00i
  g[2] = -cosf(am)*st;   // u01r
  g[3] = -sinf(am)*st;   // u01i
}

// ---------------------------------------------------------------------------
// Main: 4 waves/block, TWO batch elements per wave as independent scalar
// pipelines (ILP-2, latency hiding within the wave).
// ---------------------------------------------------------------------------
__global__ __launch_bounds__(256) void qbranch_main(
    const float* __restrict__ x,     // (B,8)
    const float* __restrict__ gates, // 16 gates x 4 floats
    const float* __restrict__ Wm,    // (8,64)
    const float* __restrict__ bias,  // (64)
    const float* __restrict__ gamma, // (64)
    const float* __restrict__ beta,  // (64)
    float* __restrict__ out,         // (B,64)
    int B)
{
  const int lane = threadIdx.x & 63;
  const int wid  = threadIdx.x >> 6;
  const int bA   = blockIdx.x * 8 + wid * 2;
  const int bB   = bA + 1;
  if (bA >= B) return;
  const int bBl  = (bB < B) ? bB : bA;

  // --- trig: lanes 0..15 elem A (2w: cos, 2w+1: sin), 16..31 elem B --------
  float val = 0.f;
  if (lane < 32) {
    const int e = lane >> 4;
    const int t = lane & 15;
    float xv = x[(e ? bBl : bA)*8 + (t >> 1)];
    float th = 1.f - 2.f / (__expf(2.f*xv) + 1.f);   // tanh
    float ha = th * (PI_F * 0.5f);
    val = (t & 1) ? __sinf(ha) : __cosf(ha);
  }

  const int l5=(lane>>5)&1, l4=(lane>>4)&1, l3=(lane>>3)&1,
            l2=(lane>>2)&1, l1=(lane>>1)&1, l0=lane&1;
  float m0A=__shfl(val, 0+l5,64), m0B=__shfl(val,16+ 0+l5,64);
  float m1A=__shfl(val, 2+l4,64), m1B=__shfl(val,16+ 2+l4,64);
  float m2A=__shfl(val, 4+l3,64), m2B=__shfl(val,16+ 4+l3,64);
  float m3A=__shfl(val, 6+l2,64), m3B=__shfl(val,16+ 6+l2,64);
  float m4A=__shfl(val, 8+l1,64), m4B=__shfl(val,16+ 8+l1,64);
  float m5A=__shfl(val,10+l0,64), m5B=__shfl(val,16+10+l0,64);
  float c6A=__shfl(val,12,64), s6A=__shfl(val,13,64);
  float c7A=__shfl(val,14,64), s7A=__shfl(val,15,64);
  float c6B=__shfl(val,28,64), s6B=__shfl(val,29,64);
  float c7B=__shfl(val,30,64), s7B=__shfl(val,31,64);

  const float pA = m0A*m1A*m2A*m3A*m4A*m5A;
  const float pB = m0B*m1B*m2B*m3B*m4B*m5B;

  // product state: amp(p) = mag(p) * (-i)^popc(p)
  float arA[4], aiA[4], arB[4], aiB[4];
  {
    const float magA[4] = { pA*c6A*c7A, pA*c6A*s7A, pA*s6A*c7A, pA*s6A*s7A };
    const float magB[4] = { pB*c6B*c7B, pB*c6B*s7B, pB*s6B*c7B, pB*s6B*s7B };
    const int kl = __popc(lane);
#pragma unroll
    for (int r = 0; r < 4; ++r) {
      const int k = kl + ((r >> 1) & 1) + (r & 1);
      float sA = (k & 2) ? -magA[r] : magA[r];
      float sB = (k & 2) ? -magB[r] : magB[r];
      arA[r] = (k & 1) ? 0.f : sA;  aiA[r] = (k & 1) ? -sA : 0.f;
      arB[r] = (k & 1) ? 0.f : sB;  aiB[r] = (k & 1) ? -sB : 0.f;
    }
  }

  const f32x4* G = (const f32x4*)gates;

  // --- layer 0 Rot gates (A = I) ------------------------------------------
  applyGP<0x20, 0, 0x20, 0>(arA, aiA, arB, aiB, G +  0, lane);
  applyGP<0x10, 0, 0x10, 0>(arA, aiA, arB, aiB, G +  1, lane);
  applyGP<0x08, 0, 0x08, 0>(arA, aiA, arB, aiB, G +  2, lane);
  applyGP<0x04, 0, 0x04, 0>(arA, aiA, arB, aiB, G +  3, lane);
  applyGP<0x02, 0, 0x02, 0>(arA, aiA, arB, aiB, G +  4, lane);
  applyGP<0x01, 0, 0x01, 0>(arA, aiA, arB, aiB, G +  5, lane);
  applyGP<0x00, 2, 0x00, 2>(arA, aiA, arB, aiB, G +  6, lane);
  applyGP<0x00, 1, 0x00, 1>(arA, aiA, arB, aiB, G +  7, lane);

  // --- layer 1 Rot gates (CNOT ring r=1 absorbed) -------------------------
  applyGP<0x30, 0, 0x1F, 3>(arA, aiA, arB, aiB, G +  8, lane);
  applyGP<0x18, 0, 0x30, 0>(arA, aiA, arB, aiB, G +  9, lane);
  applyGP<0x0C, 0, 0x38, 0>(arA, aiA, arB, aiB, G + 10, lane);
  applyGP<0x06, 0, 0x3C, 0>(arA, aiA, arB, aiB, G + 11, lane);
  applyGP<0x03, 0, 0x3E, 0>(arA, aiA, arB, aiB, G + 12, lane);
  applyGP<0x01, 2, 0x3F, 0>(arA, aiA, arB, aiB, G + 13, lane);
  applyGP<0x00, 3, 0x3F, 2>(arA, aiA, arB, aiB, G + 14, lane);
  applyGP<0x30, 1, 0x3F, 3>(arA, aiA, arB, aiB, G + 15, lane);

  // --- Z expectations with A2 sign masks (both elements) ------------------
  float zpA[8], zpB[8];
#pragma unroll
  for (int e = 0; e < 2; ++e) {
    const float* ar = e ? arB : arA;
    const float* ai = e ? aiB : aiA;
    float* zp = e ? zpB : zpA;
    const float pp0 = fmaf(ar[0], ar[0], ai[0]*ai[0]);
    const float pp1 = fmaf(ar[1], ar[1], ai[1]*ai[1]);
    const float pp2 = fmaf(ar[2], ar[2], ai[2]*ai[2]);
    const float pp3 = fmaf(ar[3], ar[3], ai[3]*ai[3]);
    const float s01 = pp0 + pp1, d01 = pp0 - pp1;
    const float s23 = pp2 + pp3, d23 = pp2 - pp3;
    const float q0 = s01 + s23, q1 = d01 + d23;
    const float q2 = s01 - s23, q3 = d01 - d23;
    zp[0] = (__popc(lane & 0x39) & 1) ? -q2 : q2;
    zp[1] = (__popc(lane & 0x3C) & 1) ? -q3 : q3;
    zp[2] = (__popc(lane & 0x27) & 1) ? -q3 : q3;
    zp[3] = (__popc(lane & 0x0C) & 1) ? -q0 : q0;
    zp[4] = (__popc(lane & 0x19) & 1) ? -q3 : q3;
    zp[5] = (__popc(lane & 0x33) & 1) ? -q0 : q0;
    zp[6] = (__popc(lane & 0x26) & 1) ? -q1 : q1;
    zp[7] = (__popc(lane & 0x0C) & 1) ? -q3 : q3;
  }

  // --- split-butterfly reduce (both elements, independent chains) ---------
  const bool lb0 = (lane & 1) != 0, lb1 = (lane & 2) != 0, lb2 = (lane & 4) != 0;
  float zsE[2];
#pragma unroll
  for (int e = 0; e < 2; ++e) {
    const float* zp = e ? zpB : zpA;
    float u[4];
#pragma unroll
    for (int k = 0; k < 4; ++k) {
      float snd = lb0 ? zp[k] : zp[k+4];
      u[k] = (lb0 ? zp[k+4] : zp[k]) + lxor<1>(snd, lane);
    }
    float v2[2];
#pragma unroll
    for (int k = 0; k < 2; ++k) {
      float snd = lb1 ? u[k] : u[k+2];
      v2[k] = (lb1 ? u[k+2] : u[k]) + lxor<2>(snd, lane);
    }
    float snd3 = lb2 ? v2[0] : v2[1];
    float zs = (lb2 ? v2[1] : v2[0]) + lxor<4>(snd3, lane);
    zs += lxor< 8>(zs, lane);
    zs += lxor<16>(zs, lane);
    zs += lxor<32>(zs, lane);
    zsE[e] = zs;
  }

  // --- projection (8 -> 64): z via readlane (SGPR), Wm column shared ------
  const int j = lane;
  const float w0 = Wm[0*64+j], w1 = Wm[1*64+j], w2 = Wm[2*64+j], w3 = Wm[3*64+j];
  const float w4 = Wm[4*64+j], w5 = Wm[5*64+j], w6 = Wm[6*64+j], w7 = Wm[7*64+j];
  const float bj = bias[j], gj = gamma[j], btj = beta[j];

  float hE[2];
#pragma unroll
  for (int e = 0; e < 2; ++e) {
    const float zs = zsE[e];
    float h = bj;
    h = fmaf(breadl<0>(zs), w0, h);
    h = fmaf(breadl<4>(zs), w1, h);
    h = fmaf(breadl<2>(zs), w2, h);
    h = fmaf(breadl<6>(zs), w3, h);
    h = fmaf(breadl<1>(zs), w4, h);
    h = fmaf(breadl<5>(zs), w5, h);
    h = fmaf(breadl<3>(zs), w6, h);
    h = fmaf(breadl<7>(zs), w7, h);
    hE[e] = h;
  }

  // --- LayerNorm: fused sum/sumsq butterfly (both elements) ---------------
#pragma unroll
  for (int e = 0; e < 2; ++e) {
    const float h = hE[e];
    float S = h, Q = h*h;
    float snd4 = lb0 ? S : Q;
    float acc = (lb0 ? Q : S) + lxor<1>(snd4, lane);
    acc += lxor< 2>(acc, lane);
    acc += lxor< 4>(acc, lane);
    acc += lxor< 8>(acc, lane);
    acc += lxor<16>(acc, lane);
    acc += lxor<32>(acc, lane);
    const float Ssum = breadl<0>(acc);
    const float Qsum = breadl<1>(acc);
    const float mu  = Ssum * (1.f/64.f);
    const float var = fmaf(-mu, mu, Qsum * (1.f/64.f));
    const float o = fmaf(gj * (h - mu), rsqrtf(var + 1e-5f), btj);
    if (e == 0)       out[bA*64 + j] = o;
    else if (bB < B)  out[bB*64 + j] = o;
  }
}

// ---------------------------------------------------------------------------
extern "C" void kernel_launch(void* const* d_in, const int* in_sizes, int n_in,
                              void* d_out, int out_size, void* d_ws, size_t ws_size,
                              hipStream_t stream)
{
  const float* x       = (const float*)d_in[0];
  const float* weights = (const float*)d_in[1];
  const float* Wm      = (const float*)d_in[2];
  const float* bias    = (const float*)d_in[3];
  const float* gamma   = (const float*)d_in[4];
  const float* beta    = (const float*)d_in[5];
  float* out   = (float*)d_out;
  float* gates = (float*)d_ws;   // 16 gates * 4 floats

  const int B = in_sizes[0] / 8;

  hipLaunchKernelGGL(qbranch_setup, dim3(1), dim3(64), 0, stream, weights, gates);
  hipLaunchKernelGGL(qbranch_main, dim3((B + 7) / 8), dim3(256), 0, stream,
                     x, gates, Wm, bias, gamma, beta, out, B);
}

// Round 9
// 27.640 us; speedup vs baseline: 1.3898x; 1.3898x over previous
//
#include <hip/hip_runtime.h>
#include <math.h>

#define PI_F 3.14159265358979323846f

typedef float f32x4v __attribute__((ext_vector_type(4)));

// ===========================================================================
// Compile-time Pauli engine.
// Convention: string = i^ph * Prod_u X^{x_u} Z^{z_u}  (X left of Z per wire).
//  - multiply:  ph += 2*popc(a.z & b.x); x^=; z^=
//  - CNOT(c,t) conjugation: x_t ^= x_c; z_c ^= z_t; ph unchanged
//    (verified on X_c,Z_t,Y_c,Y_t,Y_cY_t,X_cZ_t by hand)
// Circuit: after layer-0 Rots the state is a product state (Bloch b_w).
// Ring2^ Z_w Ring2 = Z-string S_w;  Rots1^ Z Rots1 per wire = gx X+gy Y+gz Z,
// g = (-sin(th1)cos(phi1), sin(th1)sin(phi1), cos(th1)).
// Ring1 conjugation order: (7,0),(6,7),(5,6),(4,5),(3,4),(2,3),(1,2),(0,1).
// z_w = sum over 3^|S_w| terms: sign * prod g * prod bloch-components.
// ===========================================================================
struct PS { int x, z, ph; };

constexpr int SLEN_[8]      = {3,3,2,2,3,3,4,4};
constexpr int SWIRES_[8][4] = {{2,4,6,0},{3,5,7,0},{0,2,0,0},{1,3,0,0},
                               {0,2,4,0},{1,3,5,0},{0,2,4,6},{1,3,5,7}};
constexpr int NCODE_[8]     = {27,27,9,9,27,27,81,81};
constexpr int NTERMS = 288;

constexpr int cpopc(int v){ int c=0; while(v){ c += v&1; v >>= 1; } return c; }

constexpr PS pmul(PS a, PS b) {
  return PS{ a.x ^ b.x, a.z ^ b.z, (a.ph + b.ph + 2*cpopc(a.z & b.x)) & 3 };
}
constexpr PS pcnot(PS s, int c, int t) {
  PS r = s;
  if ((s.x >> c) & 1) r.x ^= (1 << t);
  if ((s.z >> t) & 1) r.z ^= (1 << c);
  return r;
}
constexpr PS buildTerm(int w, int code) {
  PS s{0,0,0};
  int cc = code;
  for (int i = 0; i < SLEN_[w]; ++i) {
    int v = SWIRES_[w][i];
    int k = cc % 3; cc /= 3;              // 0->X, 1->Y, 2->Z
    PS comp = (k==0) ? PS{1<<v, 0, 0} : (k==1) ? PS{1<<v, 1<<v, 1} : PS{0, 1<<v, 0};
    s = pmul(s, comp);
  }
  for (int i = 7; i >= 0; --i) s = pcnot(s, i, (i+1)&7);   // Ring1 conj
  return s;
}
constexpr int wOf(int t)   { int w=0, acc=0; while (t >= acc + NCODE_[w]) { acc += NCODE_[w]; ++w; } return w; }
constexpr int codeOf(int t){ int w=0, acc=0; while (t >= acc + NCODE_[w]) { acc += NCODE_[w]; ++w; } return t - acc; }
constexpr PS termOf(int t) { return buildTerm(wOf(t), codeOf(t)); }
constexpr float signOf(int t) {
  PS s = termOf(t);
  int e = (s.ph - cpopc(s.x & s.z)) & 3;  // <XZ> = -i<Y>: remove i per Y
  return (e == 0) ? 1.0f : -1.0f;
}

// ---- guaranteed compile-time term evaluation (templates) ------------------
template<int T, int U>
static __device__ __forceinline__ float tfac(const float* bx, const float* by, const float* bz) {
  constexpr PS s = termOf(T);
  constexpr bool xb = (s.x >> U) & 1, zb = (s.z >> U) & 1;
  if constexpr (xb && zb) return by[U];
  else if constexpr (xb)  return bx[U];
  else if constexpr (zb)  return bz[U];
  else                    return 1.0f;
}
template<int T>
static __device__ __forceinline__ float teval(const float* bx, const float* by, const float* bz) {
  return tfac<T,0>(bx,by,bz) * tfac<T,1>(bx,by,bz) * tfac<T,2>(bx,by,bz) * tfac<T,3>(bx,by,bz)
       * tfac<T,4>(bx,by,bz) * tfac<T,5>(bx,by,bz) * tfac<T,6>(bx,by,bz) * tfac<T,7>(bx,by,bz);
}
template<int T>
static __device__ __forceinline__ void evalTerms(const float* __restrict__ cf,
    const float* bx, const float* by, const float* bz, float* zv) {
  if constexpr (T < NTERMS) {
    constexpr int wi = wOf(T);
    zv[wi] = fmaf(cf[T], teval<T>(bx,by,bz), zv[wi]);
    evalTerms<T+1>(cf, bx, by, bz, zv);
  }
}

// ===========================================================================
// Setup: ws layout (floats):
//  [0..31]  U0 params per qubit: u00r,u00i,u01r,u01i (layer-0 Rot)
//  [32..39] Wsum_w = sum_j W[w][j]
//  [40..47] 2*Wb_w = 2*sum_j W[w][j] b_j
//  [48] bsum   [49] bb = sum b^2
//  [64..127] G[w][w'] = sum_j W[w][j] W[w'][j]
//  [128..415] coeff[t] = signOf(t) * prod_i g[v_i][k_i]
// ===========================================================================
__global__ void qbranch_setup(const float* __restrict__ weights,
                              const float* __restrict__ Wm,
                              const float* __restrict__ bias,
                              float* __restrict__ ws)
{
  __shared__ float g[8][3];
  const int t = threadIdx.x;
  if (t < 8) {
    // layer-0 Rot matrix entries (reference-validated formulas)
    float phi = weights[t*3 + 0], th = weights[t*3 + 1], om = weights[t*3 + 2];
    float ct = cosf(th*0.5f), st = sinf(th*0.5f);
    float ap = (phi + om)*0.5f, am = (phi - om)*0.5f;
    ws[t*4+0] =  cosf(ap)*ct;   // u00r
    ws[t*4+1] = -sinf(ap)*ct;   // u00i
    ws[t*4+2] = -cosf(am)*st;   // u01r
    ws[t*4+3] = -sinf(am)*st;   // u01i
    // layer-1 Heisenberg g-vector (FULL angles)
    float phi1 = weights[(8+t)*3 + 0], th1 = weights[(8+t)*3 + 1];
    float s1 = sinf(th1), c1 = cosf(th1);
    g[t][0] = -s1*cosf(phi1);
    g[t][1] =  s1*sinf(phi1);
    g[t][2] =  c1;
  }
  if (t >= 8 && t < 16) {
    int w = t - 8; float s = 0.f;
    for (int j = 0; j < 64; ++j) s += Wm[w*64+j];
    ws[32+w] = s;
  }
  if (t >= 16 && t < 24) {
    int w = t - 16; float s = 0.f;
    for (int j = 0; j < 64; ++j) s += Wm[w*64+j]*bias[j];
    ws[40+w] = 2.f*s;
  }
  if (t == 24) { float s=0.f; for (int j=0;j<64;++j) s += bias[j];          ws[48] = s; }
  if (t == 25) { float s=0.f; for (int j=0;j<64;++j) s += bias[j]*bias[j];  ws[49] = s; }
  if (t >= 64 && t < 128) {
    int idx = t - 64, a = idx >> 3, b = idx & 7; float s = 0.f;
    for (int j = 0; j < 64; ++j) s += Wm[a*64+j]*Wm[b*64+j];
    ws[64+idx] = s;
  }
  __syncthreads();
  if (t < NTERMS) {
    int w = wOf(t), code = codeOf(t);
    float c = signOf(t);
    int cc = code;
    for (int i = 0; i < SLEN_[w]; ++i) {
      int k = cc % 3; cc /= 3;
      c *= g[SWIRES_[w][i]][k];
    }
    ws[128 + t] = c;
  }
}

// ===========================================================================
// Main: one batch element per LANE (no cross-lane for the circuit).
// 64-thread blocks; each wave covers 64 elements; projection via readlane
// e-loop with coalesced stores.
// ===========================================================================
static __device__ __forceinline__ float rl(float v, int e) {
  return __builtin_bit_cast(float,
    __builtin_amdgcn_readlane(__builtin_bit_cast(int, v), e));
}

__global__ __launch_bounds__(64) void qbranch_main(
    const float* __restrict__ x,     // (B,8)
    const float* __restrict__ ws,    // setup products
    const float* __restrict__ Wm,    // (8,64)
    const float* __restrict__ bias,  // (64)
    const float* __restrict__ gamma, // (64)
    const float* __restrict__ beta,  // (64)
    float* __restrict__ out,         // (B,64)
    int B)
{
  const int lane = threadIdx.x;
  const int base = blockIdx.x * 64;
  const int elem = base + lane;
  const int el   = (elem < B) ? elem : (B - 1);

  // --- per-lane input + Bloch vectors -------------------------------------
  const f32x4v xa = *(const f32x4v*)(x + (size_t)el*8);
  const f32x4v xb_ = *(const f32x4v*)(x + (size_t)el*8 + 4);

  float bx[8], by[8], bz[8];
#pragma unroll
  for (int w = 0; w < 8; ++w) {
    const float xv = (w < 4) ? xa[w] : xb_[w-4];
    const float th = 1.f - 2.f / (__expf(2.f*xv) + 1.f);   // tanh
    const float ha = th * (PI_F * 0.5f);                    // theta/2
    const float c = __cosf(ha), s = __sinf(ha);
    const float u00r = ws[w*4+0], u00i = ws[w*4+1];
    const float u01r = ws[w*4+2], u01i = ws[w*4+3];
    // chi = Rot0 * (c, -i s);  u10=-conj(u01), u11=conj(u00)
    const float x0r =  u00r*c + u01i*s;
    const float x0i =  u00i*c - u01r*s;
    const float x1r = -u01r*c - u00i*s;
    const float x1i =  u01i*c - u00r*s;
    bx[w] = 2.f*(x0r*x1r + x0i*x1i);
    by[w] = 2.f*(x0r*x1i - x0i*x1r);
    bz[w] = x0r*x0r + x0i*x0i - x1r*x1r - x1i*x1i;
  }

  // --- z expectations: 288 compile-time-structured terms ------------------
  float zv[8] = {0.f,0.f,0.f,0.f,0.f,0.f,0.f,0.f};
  evalTerms<0>(ws + 128, bx, by, bz, zv);

  // --- LN stats via precomputed quadratic form ----------------------------
  const float* Wsum = ws + 32;
  const float* Wb2  = ws + 40;
  const float* G    = ws + 64;
  float mu = ws[48];
#pragma unroll
  for (int w = 0; w < 8; ++w) mu = fmaf(zv[w], Wsum[w], mu);
  mu *= (1.f/64.f);
  float q = ws[49];
#pragma unroll
  for (int w = 0; w < 8; ++w) {
    float tw = 0.f;
#pragma unroll
    for (int w2 = 0; w2 < 8; ++w2) tw = fmaf(G[w*8+w2], zv[w2], tw);
    q = fmaf(zv[w], tw, q);
    q = fmaf(zv[w], Wb2[w], q);
  }
  const float var = fmaf(-mu, mu, q * (1.f/64.f));
  const float rs  = rsqrtf(var + 1e-5f);

  // --- projection + LN apply: wave-parallel over outputs, loop elements ---
  const int j = lane;
  const float w0 = Wm[0*64+j], w1 = Wm[1*64+j], w2 = Wm[2*64+j], w3 = Wm[3*64+j];
  const float w4 = Wm[4*64+j], w5 = Wm[5*64+j], w6 = Wm[6*64+j], w7 = Wm[7*64+j];
  const float bj = bias[j], gj = gamma[j], btj = beta[j];

  const int cnt = (B - base < 64) ? (B - base) : 64;
  float* po = out + (size_t)base*64 + j;
#pragma unroll 2
  for (int e = 0; e < cnt; ++e) {
    const float s0 = rl(zv[0], e), s1 = rl(zv[1], e), s2 = rl(zv[2], e), s3 = rl(zv[3], e);
    const float s4 = rl(zv[4], e), s5 = rl(zv[5], e), s6 = rl(zv[6], e), s7 = rl(zv[7], e);
    const float smu = rl(mu, e), srs = rl(rs, e);
    float h = bj;
    h = fmaf(s0, w0, h); h = fmaf(s1, w1, h); h = fmaf(s2, w2, h); h = fmaf(s3, w3, h);
    h = fmaf(s4, w4, h); h = fmaf(s5, w5, h); h = fmaf(s6, w6, h); h = fmaf(s7, w7, h);
    const float o = fmaf((h - smu) * srs, gj, btj);
    *po = o;
    po += 64;
  }
}

// ---------------------------------------------------------------------------
extern "C" void kernel_launch(void* const* d_in, const int* in_sizes, int n_in,
                              void* d_out, int out_size, void* d_ws, size_t ws_size,
                              hipStream_t stream)
{
  const float* x       = (const float*)d_in[0];
  const float* weights = (const float*)d_in[1];
  const float* Wm      = (const float*)d_in[2];
  const float* bias    = (const float*)d_in[3];
  const float* gamma   = (const float*)d_in[4];
  const float* beta    = (const float*)d_in[5];
  float* out = (float*)d_out;
  float* ws  = (float*)d_ws;   // 416 floats used

  const int B = in_sizes[0] / 8;

  hipLaunchKernelGGL(qbranch_setup, dim3(1), dim3(512), 0, stream, weights, Wm, bias, ws);
  hipLaunchKernelGGL(qbranch_main, dim3((B + 63) / 64), dim3(64), 0, stream,
                     x, ws, Wm, bias, gamma, beta, out, B);
}